// Round 11
// baseline (309.512 us; speedup 1.0000x reference)
//
#include <hip/hip_runtime.h>

typedef __attribute__((ext_vector_type(8)))  short s8b;    // 8 x bf16
typedef __attribute__((ext_vector_type(16))) float f32x16; // mfma C/D

static constexpr int   kBatch    = 2097152;
static constexpr float kActScale = 1.0f / 12.0f;
static constexpr float kAct2     = 1.0f / 6.0f;   // 2*ACT_SCALE

// fp32 table: [4096,4128) aout ; [4128] cref
__device__ float  g_tab[4136];
// bf16 hi/lo weight tables, row-major 32x32 each:
// [0]=A0 hi [1]=A0 lo [2]=A1 hi [3]=A1 lo [4]=A1T hi [5]=A1T lo [6]=A0T hi [7]=A0T lo
__device__ __attribute__((aligned(16))) ushort g_bt[8][1024];

__device__ __forceinline__ float rcp_f(float x) { return __fdividef(1.0f, x); }
__device__ __forceinline__ float sp_only(float x) {
    float e = __expf(-fabsf(x));
    return fmaxf(x, 0.0f) + __logf(1.0f + e);
}
__device__ __forceinline__ float sig_only(float x) {
    float e = __expf(-fabsf(x));
    float r = rcp_f(1.0f + e);
    return (x >= 0.0f) ? r : e * r;
}
__device__ __forceinline__ float sp_sig(float x, float& sig) {
    float e  = __expf(-fabsf(x));
    float oe = 1.0f + e;
    float r  = rcp_f(oe);
    sig = (x >= 0.0f) ? r : e * r;
    return fmaxf(x, 0.0f) + __logf(oe);
}

__device__ __forceinline__ uint  bf16u(float x) {
    uint u = __float_as_uint(x);
    return (u + 0x7FFFu + ((u >> 16) & 1u)) >> 16;      // RNE
}
__device__ __forceinline__ float bf16f(uint h) { return __uint_as_float(h << 16); }
// packed RNE convert: low16 = bf16(lo), high16 = bf16(hi) -- 1 instruction
__device__ __forceinline__ uint cvt_pk_bf16(float lo, float hi) {
    uint r;
    asm("v_cvt_pk_bf16_f32 %0, %1, %2" : "=v"(r) : "v"(lo), "v"(hi));
    return r;
}

// ---------------- prep: bf16 hi/lo weight tables + aout + cref ---------------
__global__ __launch_bounds__(256) void icnn_prep(
    const float* __restrict__ rawA0, const float* __restrict__ rawA1,
    const float* __restrict__ rawAout,
    const float* __restrict__ W1,  const float* __restrict__ b1,
    const float* __restrict__ Wc0, const float* __restrict__ bc0,
    const float* __restrict__ Wc1, const float* __restrict__ bc1,
    const float* __restrict__ wout)
{
    __shared__ float sA0[1024], sA1[1024], sAout[32];
    const int t = threadIdx.x;
    for (int k = t; k < 1024; k += 256) sA0[k] = sp_only(rawA0[k]);
    for (int k = t; k < 1024; k += 256) sA1[k] = sp_only(rawA1[k]);
    if (t < 32) { float v = sp_only(rawAout[t]); sAout[t] = v; g_tab[4096 + t] = v; }
    __syncthreads();
    for (int k = t; k < 1024; k += 256) {
        float v0 = sA0[k];
        uint h0 = bf16u(v0);
        g_bt[0][k] = (ushort)h0; g_bt[1][k] = (ushort)bf16u(v0 - bf16f(h0));
        float v1 = sA1[k];
        uint h1 = bf16u(v1);
        g_bt[2][k] = (ushort)h1; g_bt[3][k] = (ushort)bf16u(v1 - bf16f(h1));
        float v2 = sA1[(k & 31) * 32 + (k >> 5)];     // A1T[i][j] = A1[j][i]
        uint h2 = bf16u(v2);
        g_bt[4][k] = (ushort)h2; g_bt[5][k] = (ushort)bf16u(v2 - bf16f(h2));
        float v3 = sA0[(k & 31) * 32 + (k >> 5)];     // A0T
        uint h3 = bf16u(v3);
        g_bt[6][k] = (ushort)h3; g_bt[7][k] = (ushort)bf16u(v3 - bf16f(h3));
    }

    // cref: exact fp32 gradient dW/dI1 at z0 = 0 (wave-0 lanes 0..31)
    if (t < 32) {
        const int i = t;
        float sa, sc0v;
        float zi = sp_sig(b1[i], sa);
        float u = 0.0f;
        for (int j = 0; j < 32; j++) u = fmaf(sA0[i * 32 + j], __shfl(zi, j, 64), u);
        float su; float t0 = sp_sig(u, su);
        float d0 = kAct2 * t0 * su;
        float spc = sp_sig(bc0[i], sc0v);
        float zn = fmaf(kActScale * t0, t0, spc);
        float u1 = 0.0f;
        for (int j = 0; j < 32; j++) u1 = fmaf(sA1[i * 32 + j], __shfl(zn, j, 64), u1);
        float su1; float t1 = sp_sig(u1, su1);
        float d1 = sAout[i] * kAct2 * t1 * su1;
        float contrib = Wc1[2 * i] * sAout[i] * sig_only(bc1[i]);
        float g = 0.0f;
        for (int j = 0; j < 32; j++) g = fmaf(sA1[j * 32 + i], __shfl(d1, j, 64), g);
        contrib = fmaf(Wc0[2 * i], g * sc0v, contrib);
        float gu0 = g * d0;
        float ga = 0.0f;
        for (int j = 0; j < 32; j++) ga = fmaf(sA0[j * 32 + i], __shfl(gu0, j, 64), ga);
        ga *= sa;
        contrib = fmaf(W1[2 * i], ga, contrib);
        for (int off = 16; off >= 1; off >>= 1)
            contrib += __shfl_down(contrib, off, 32);
        if (i == 0) g_tab[4128] = wout[0] + contrib;
    }
}

// A-frag read from the bf16 region (dword view, 4-B aligned -> 4x ds_read_b32;
// memcpy = char semantics -> cannot be hoisted above the ushort stores).
#define RD1S(F, T, KH) { \
    const uint* p = hb + (col + 32 * (T)) * 17 + 4 * half + 8 * (KH); \
    union { s8b v; uint d[4]; } u_; \
    __builtin_memcpy(&u_.d[0], p, 16); \
    F = u_.v; }

#define RDALLS(P) \
    s8b P##00, P##01, P##10, P##11; \
    RD1S(P##00, 0, 0) RD1S(P##01, 0, 1) RD1S(P##10, 1, 0) RD1S(P##11, 1, 1)

// D = Act_bf16 * (Whi + Wlo): 4 mfma per 32x32 tile, 8 per matvec
#define MATVEC(M, P, ACCA, ACCB) { \
    const s8b* Bh = (const s8b*)&g_bt[2 * (M)][0]; \
    const s8b* Bl = (const s8b*)&g_bt[2 * (M) + 1][0]; \
    const int i0 = col * 4 + half, i1 = i0 + 2; \
    s8b bh0 = Bh[i0], bh1 = Bh[i1], bl0 = Bl[i0], bl1 = Bl[i1]; \
    ACCA = __builtin_amdgcn_mfma_f32_32x32x16_bf16(P##00, bh0, ACCA, 0, 0, 0); \
    ACCA = __builtin_amdgcn_mfma_f32_32x32x16_bf16(P##01, bh1, ACCA, 0, 0, 0); \
    ACCA = __builtin_amdgcn_mfma_f32_32x32x16_bf16(P##00, bl0, ACCA, 0, 0, 0); \
    ACCA = __builtin_amdgcn_mfma_f32_32x32x16_bf16(P##01, bl1, ACCA, 0, 0, 0); \
    ACCB = __builtin_amdgcn_mfma_f32_32x32x16_bf16(P##10, bh0, ACCB, 0, 0, 0); \
    ACCB = __builtin_amdgcn_mfma_f32_32x32x16_bf16(P##11, bh1, ACCB, 0, 0, 0); \
    ACCB = __builtin_amdgcn_mfma_f32_32x32x16_bf16(P##10, bl0, ACCB, 0, 0, 0); \
    ACCB = __builtin_amdgcn_mfma_f32_32x32x16_bf16(P##11, bl1, ACCB, 0, 0, 0); }

// ---------------- main: one wave = 64 rows, MFMA matvecs ---------------------
// C-frag (row,col): col = lane&31, row = 4*(lane>>5) + (j&3) + 8*(j>>2).
// Per-wave LDS, DISJOINT regions (R10's aliasing forced 127-reg peak -> spill):
//   hb  = uint[64][17]  bf16 activations (odd dword stride, conflict-free)
//   sw  = uint[64][33]  f32: d0 (Stage B->D, read-then-overwrite), raw folds
// d0 lives in LDS, not 32 VGPRs. Peak live ~80 regs -> no spill at VGPR=64-96.
__global__ __launch_bounds__(256) __attribute__((amdgpu_waves_per_eu(3, 3)))
void icnn_main(
    const float* __restrict__ eps,
    const float* __restrict__ W1,  const float* __restrict__ b1,
    const float* __restrict__ Wc0, const float* __restrict__ bc0,
    const float* __restrict__ Wc1, const float* __restrict__ bc1,
    const float* __restrict__ wout,
    float* __restrict__ out)
{
    __shared__ uint sbuf[4 * (64 * 33 + 64 * 17)];     // 51200 B
    const int tid  = threadIdx.x;
    const int lane = tid & 63, wib = tid >> 6;
    uint*   __restrict__ sw  = sbuf + wib * (64 * 33 + 64 * 17);  // f32 region
    uint*   __restrict__ hb  = sw + 64 * 33;                      // bf16 region
    ushort* __restrict__ hbh = (ushort*)hb;
    const int col = lane & 31, half = lane >> 5;
    const long rowg = (long)(blockIdx.x * 4 + wib) * 64 + lane;

    const float e11 = eps[rowg * 3 + 0];
    const float e22 = eps[rowg * 3 + 1];
    const float e12 = eps[rowg * 3 + 2];
    const float x1 = e11 + e22;
    const float x2 = e11 * e11 + 2.0f * e12 * e12 + e22 * e22;

    float g0 = wout[0], gq = wout[1];

    // ---- Stage A: z = sp(W1 z0 + b1) exactly per-row; packed bf16 pairs
    #pragma unroll
    for (int u = 0; u < 16; u++) {
        float a0 = fmaf(W1[4 * u],     x1, fmaf(W1[4 * u + 1], x2, b1[2 * u]));
        float a1 = fmaf(W1[4 * u + 2], x1, fmaf(W1[4 * u + 3], x2, b1[2 * u + 1]));
        hb[lane * 17 + u] = cvt_pk_bf16(sp_only(a0), sp_only(a1));
    }

    // ---- Stage B: u0 = Z A0^T (MFMA); d0 -> f32 LDS; zn -> bf16 junction
    RDALLS(z)
    f32x16 acc0a = {}, acc0b = {};
    MATVEC(0, z, acc0a, acc0b)

    // c0 pre-activation via tiny MFMA (rank-2, bf16 x -> negligible err)
    const float x1s = __shfl(x1, col),      x2s = __shfl(x2, col);
    const float x1o = __shfl(x1, 32 + col), x2o = __shfl(x2, 32 + col);
    union { s8b v; uint d[4]; } xa0, xa1, wb;
    xa0.d[1] = xa0.d[2] = xa0.d[3] = 0;
    xa1.d[1] = xa1.d[2] = xa1.d[3] = 0;
    wb.d[1] = wb.d[2] = wb.d[3] = 0;
    xa0.d[0] = half ? 0u : (bf16u(x1s) | (bf16u(x2s) << 16));
    xa1.d[0] = half ? 0u : (bf16u(x1o) | (bf16u(x2o) << 16));
    wb.d[0]  = half ? 0u : (bf16u(Wc0[2 * col]) | (bf16u(Wc0[2 * col + 1]) << 16));
    f32x16 zz = {};
    f32x16 c0pa = __builtin_amdgcn_mfma_f32_32x32x16_bf16(xa0.v, wb.v, zz, 0, 0, 0);
    f32x16 c0pb = __builtin_amdgcn_mfma_f32_32x32x16_bf16(xa1.v, wb.v, zz, 0, 0, 0);

    const float bc0c = bc0[col];
    #pragma unroll
    for (int j = 0; j < 16; j++) {
        const int rowl = 4 * half + (j & 3) + 8 * (j >> 2);
        float su; float t = sp_sig(acc0a[j], su);
        sw[rowl * 33 + col] = __float_as_uint(kAct2 * t * su);          // d0a
        float zna = fmaf(kActScale * t, t, sp_only(c0pa[j] + bc0c));
        float su2; float t2 = sp_sig(acc0b[j], su2);
        sw[(rowl + 32) * 33 + col] = __float_as_uint(kAct2 * t2 * su2); // d0b
        float znb = fmaf(kActScale * t2, t2, sp_only(c0pb[j] + bc0c));
        uint pk = cvt_pk_bf16(zna, znb);
        hbh[rowl * 34 + col]        = (ushort)pk;
        hbh[(rowl + 32) * 34 + col] = (ushort)(pk >> 16);
    }

    // ---- Stage C: u1 = ZN A1^T (issue first; T1 fold hides mfma latency)
    RDALLS(n)
    f32x16 acc1a = {}, acc1b = {};
    MATVEC(1, n, acc1a, acc1b)

    #pragma unroll
    for (int c = 0; c < 32; c++) {
        float c1 = fmaf(Wc1[2 * c], x1, fmaf(Wc1[2 * c + 1], x2, bc1[c]));
        float w = g_tab[4096 + c] * sig_only(c1);
        g0 = fmaf(Wc1[2 * c], w, g0);
        gq = fmaf(Wc1[2 * c + 1], w, gq);
    }

    const float aoutc = g_tab[4096 + col];
    #pragma unroll
    for (int j = 0; j < 16; j++) {
        const int rowl = 4 * half + (j & 3) + 8 * (j >> 2);
        float su; float t = sp_sig(acc1a[j], su);
        float d1a = aoutc * kAct2 * t * su;
        float su2; float t2 = sp_sig(acc1b[j], su2);
        float d1b = aoutc * kAct2 * t2 * su2;
        uint pk = cvt_pk_bf16(d1a, d1b);
        hbh[rowl * 34 + col]        = (ushort)pk;
        hbh[(rowl + 32) * 34 + col] = (ushort)(pk >> 16);
    }

    // ---- Stage D: g = D1 A1; per-j: read d0 (then overwrite slot with raw g
    //      for the T2 fold), gg = g*d0 -> bf16 junction
    RDALLS(d)
    f32x16 acc2a = {}, acc2b = {};
    MATVEC(2, d, acc2a, acc2b)

    #pragma unroll
    for (int j = 0; j < 16; j++) {
        const int rowl = 4 * half + (j & 3) + 8 * (j >> 2);
        float d0a = __uint_as_float(sw[rowl * 33 + col]);
        float d0b = __uint_as_float(sw[(rowl + 32) * 33 + col]);
        sw[rowl * 33 + col]        = __float_as_uint(acc2a[j]);   // raw g
        sw[(rowl + 32) * 33 + col] = __float_as_uint(acc2b[j]);
        uint pk = cvt_pk_bf16(acc2a[j] * d0a, acc2b[j] * d0b);    // gg
        hbh[rowl * 34 + col]        = (ushort)pk;
        hbh[(rowl + 32) * 34 + col] = (ushort)(pk >> 16);
    }

    // issue Stage E matvec now; T2 fold VALU hides its latency
    RDALLS(g)
    f32x16 acc3a = {}, acc3b = {};
    MATVEC(3, g, acc3a, acc3b)

    #pragma unroll
    for (int c = 0; c < 32; c++) {
        float v  = __uint_as_float(sw[lane * 33 + c]);
        float c0 = fmaf(Wc0[2 * c], x1, fmaf(Wc0[2 * c + 1], x2, bc0[c]));
        float t2v = v * sig_only(c0);
        g0 = fmaf(Wc0[2 * c], t2v, g0);
        gq = fmaf(Wc0[2 * c + 1], t2v, gq);
    }

    // ---- Stage E: raw acc3 -> transposed T3 fold with exact sig(a)
    #pragma unroll
    for (int j = 0; j < 16; j++) {
        const int rowl = 4 * half + (j & 3) + 8 * (j >> 2);
        sw[rowl * 33 + col]        = __float_as_uint(acc3a[j]);
        sw[(rowl + 32) * 33 + col] = __float_as_uint(acc3b[j]);
    }
    #pragma unroll
    for (int c = 0; c < 32; c++) {
        float v = __uint_as_float(sw[lane * 33 + c]);
        float a = fmaf(W1[2 * c], x1, fmaf(W1[2 * c + 1], x2, b1[c]));
        float t3 = v * sig_only(a);
        g0 = fmaf(W1[2 * c], t3, g0);
        gq = fmaf(W1[2 * c + 1], t3, gq);
    }

    const float cref = g_tab[4128];
    const float dI1 = g0 - cref;
    const float dI2 = gq;
    out[rowg * 3 + 0] = fmaf(2.0f * e11, dI2, dI1);
    out[rowg * 3 + 1] = fmaf(2.0f * e22, dI2, dI1);
    out[rowg * 3 + 2] = 2.0f * e12 * dI2;
}

extern "C" void kernel_launch(void* const* d_in, const int* in_sizes, int n_in,
                              void* d_out, int out_size, void* d_ws, size_t ws_size,
                              hipStream_t stream)
{
    (void)in_sizes; (void)n_in; (void)out_size; (void)d_ws; (void)ws_size;
    const float* eps    = (const float*)d_in[0];
    const float* W1     = (const float*)d_in[1];
    const float* b1     = (const float*)d_in[2];
    const float* rawA0  = (const float*)d_in[3];
    const float* rawA1  = (const float*)d_in[4];
    const float* Wc0    = (const float*)d_in[5];
    const float* bc0    = (const float*)d_in[6];
    const float* Wc1    = (const float*)d_in[7];
    const float* bc1    = (const float*)d_in[8];
    const float* rawAout= (const float*)d_in[9];
    const float* wout   = (const float*)d_in[10];
    float* out = (float*)d_out;

    icnn_prep<<<1, 256, 0, stream>>>(rawA0, rawA1, rawAout, W1, b1, Wc0, bc0, Wc1, bc1, wout);
    icnn_main<<<kBatch / 256, 256, 0, stream>>>(eps, W1, b1, Wc0, bc0, Wc1, bc1, wout, out);
}